// Round 1
// baseline (417.471 us; speedup 1.0000x reference)
//
#include <hip/hip_runtime.h>

#define FOLD  8
#define ISIZE 256
#define OSIZE 256
#define IN_F  2048
#define OUT_F 2048
#define TB    8      // batch rows per block

// ---------------------------------------------------------------------------
// Kernel 1: global abs-max over the input (16.7M fp32).  Non-negative floats
// compare correctly as uint bit-patterns -> atomicMax on uint.
// ---------------------------------------------------------------------------
__global__ void absmax_kernel(const float4* __restrict__ in,
                              unsigned int* __restrict__ out, int n4) {
    int idx = blockIdx.x * blockDim.x + threadIdx.x;
    int stride = gridDim.x * blockDim.x;
    float m = 0.0f;
    for (int i = idx; i < n4; i += stride) {
        float4 v = in[i];
        m = fmaxf(m, fmaxf(fmaxf(fabsf(v.x), fabsf(v.y)),
                           fmaxf(fabsf(v.z), fabsf(v.w))));
    }
    #pragma unroll
    for (int off = 32; off > 0; off >>= 1)
        m = fmaxf(m, __shfl_down(m, off, 64));
    __shared__ float sm[4];
    int lane = threadIdx.x & 63;
    int wv   = threadIdx.x >> 6;
    if (lane == 0) sm[wv] = m;
    __syncthreads();
    if (threadIdx.x == 0) {
        float b = fmaxf(fmaxf(sm[0], sm[1]), fmaxf(sm[2], sm[3]));
        atomicMax(out, __float_as_uint(b));
    }
}

// ---------------------------------------------------------------------------
// Kernel 2: per block of TB=8 batch rows:
//   Phase A: y[i][r][k] = sum_f masked(clip(x)+pe)   (all 8 folds, 64KB LDS)
//   Phase B: out[r, i*256+o] = sum_k y[i][r][k] * W[i][o][k]   (fp32 FMA)
// ---------------------------------------------------------------------------
__global__ __launch_bounds__(256, 2)
void fold_linear_kernel(const float* __restrict__ in,
                        const float* __restrict__ W,
                        const float* __restrict__ pe,
                        const float* __restrict__ mn,
                        const float* __restrict__ mx,
                        const unsigned int* __restrict__ maxbits,
                        float* __restrict__ out) {
    __shared__ float y[FOLD][TB][ISIZE];   // 8*8*256*4 = 64 KB

    const int row0 = blockIdx.x * TB;
    const int k = threadIdx.x;             // 0..255 (column within a fold)

    // c = (max|x|/127) * 127, matching reference fp32 op order exactly
    const float m  = __uint_as_float(*maxbits);
    const float s0 = m / 127.0f;
    const float c  = s0 * 127.0f;

    // per-column constants in registers
    float pef[FOLD], lo[FOLD], hi[FOLD];
    #pragma unroll
    for (int f = 0; f < FOLD; ++f) pef[f] = pe[f * ISIZE + k];
    #pragma unroll
    for (int i = 0; i < FOLD; ++i) {
        lo[i] = mn[i * ISIZE + k] * c;
        hi[i] = mx[i * ISIZE + k] * c;
    }

    // -------- Phase A: masked fold-sum into LDS --------
    for (int r = 0; r < TB; ++r) {
        float acc[FOLD];
        #pragma unroll
        for (int i = 0; i < FOLD; ++i) acc[i] = 0.0f;
        const float* rowp = in + (size_t)(row0 + r) * IN_F + k;
        #pragma unroll
        for (int f = 0; f < FOLD; ++f) {
            float x = rowp[f * ISIZE];
            x = fminf(fmaxf(x, -c), c);   // clip
            x = x + pef[f];               // positional offset
            #pragma unroll
            for (int i = 0; i < FOLD; ++i) {
                // keep iff !(x < lo) && !(x > hi)  (matches reference mask)
                acc[i] += (x >= lo[i] && x <= hi[i]) ? x : 0.0f;
            }
        }
        #pragma unroll
        for (int i = 0; i < FOLD; ++i) y[i][r][k] = acc[i];
    }
    __syncthreads();

    // -------- Phase B: 8 small GEMMs, thread t owns output column o=t --------
    const int o = threadIdx.x;
    for (int i = 0; i < FOLD; ++i) {
        float acc[TB];
        #pragma unroll
        for (int r = 0; r < TB; ++r) acc[r] = 0.0f;
        const float* wrow = W + ((size_t)i * OSIZE + o) * ISIZE;
        for (int k4 = 0; k4 < ISIZE; k4 += 4) {
            const float4 w4 = *(const float4*)(wrow + k4);
            #pragma unroll
            for (int r = 0; r < TB; ++r) {
                const float4 y4 = *(const float4*)&y[i][r][k4];  // LDS broadcast
                acc[r] += y4.x * w4.x + y4.y * w4.y + y4.z * w4.z + y4.w * w4.w;
            }
        }
        #pragma unroll
        for (int r = 0; r < TB; ++r)
            out[(size_t)(row0 + r) * OUT_F + i * OSIZE + o] = acc[r];
    }
}

extern "C" void kernel_launch(void* const* d_in, const int* in_sizes, int n_in,
                              void* d_out, int out_size, void* d_ws, size_t ws_size,
                              hipStream_t stream) {
    const float* in = (const float*)d_in[0];   // [8192, 2048]
    const float* W  = (const float*)d_in[1];   // [8, 256, 256]
    const float* pe = (const float*)d_in[2];   // [1, 8, 256]
    const float* mn = (const float*)d_in[3];   // [1, 8, 256]
    const float* mx = (const float*)d_in[4];   // [1, 8, 256]
    float* out = (float*)d_out;                // [8192, 2048]
    unsigned int* maxbits = (unsigned int*)d_ws;

    const int B = 8192;
    const int n4 = B * IN_F / 4;

    // d_ws is poisoned 0xAA before every timed launch — zero the scalar.
    hipMemsetAsync(maxbits, 0, sizeof(unsigned int), stream);

    absmax_kernel<<<2048, 256, 0, stream>>>((const float4*)in, maxbits, n4);

    fold_linear_kernel<<<B / TB, 256, 0, stream>>>(in, W, pe, mn, mx, maxbits, out);
}

// Round 3
// 245.221 us; speedup vs baseline: 1.7024x; 1.7024x over previous
//
#include <hip/hip_runtime.h>

#define FOLD  8
#define ISIZE 256
#define IN_F  2048
#define OUT_F 2048
#define TBM   16                  // batch rows per block
#define NBLK  (8192 / TBM)        // 512 blocks = 2 per CU

typedef __attribute__((ext_vector_type(8))) short short8;   // 8 bf16 (4 VGPRs)
typedef __attribute__((ext_vector_type(4))) float f32x4;    // MFMA C/D frag

// round-to-nearest-even fp32 -> bf16
__device__ __forceinline__ unsigned f2bf(float f) {
    unsigned u = __float_as_uint(f);
    u += 0x7FFFu + ((u >> 16) & 1u);
    return (u >> 16);
}

// ---------------------------------------------------------------------------
// Kernel 1: global abs-max. 4096 blocks x 256 threads, exactly 4 float4 each.
// ---------------------------------------------------------------------------
__global__ void absmax_kernel(const float4* __restrict__ in,
                              unsigned int* __restrict__ out) {
    const int S = 4096 * 256;               // float4 stride
    int idx = blockIdx.x * 256 + threadIdx.x;
    float4 a = in[idx];
    float4 b = in[idx + S];
    float4 c = in[idx + 2 * S];
    float4 d = in[idx + 3 * S];
    float m = fmaxf(fmaxf(fabsf(a.x), fabsf(a.y)), fmaxf(fabsf(a.z), fabsf(a.w)));
    m = fmaxf(m, fmaxf(fmaxf(fabsf(b.x), fabsf(b.y)), fmaxf(fabsf(b.z), fabsf(b.w))));
    m = fmaxf(m, fmaxf(fmaxf(fabsf(c.x), fabsf(c.y)), fmaxf(fabsf(c.z), fabsf(c.w))));
    m = fmaxf(m, fmaxf(fmaxf(fabsf(d.x), fabsf(d.y)), fmaxf(fabsf(d.z), fabsf(d.w))));
    #pragma unroll
    for (int off = 32; off > 0; off >>= 1)
        m = fmaxf(m, __shfl_down(m, off, 64));
    __shared__ float sm[4];
    int lane = threadIdx.x & 63;
    int wv   = threadIdx.x >> 6;
    if (lane == 0) sm[wv] = m;
    __syncthreads();
    if (threadIdx.x == 0) {
        float r = fmaxf(fmaxf(sm[0], sm[1]), fmaxf(sm[2], sm[3]));
        atomicMax(out, __float_as_uint(r));
    }
}

// ---------------------------------------------------------------------------
// Kernel 2 (fast path only): W fp32 -> bf16 in MFMA B-fragment order.
// ---------------------------------------------------------------------------
__global__ void convert_w_kernel(const float* __restrict__ W,
                                 unsigned short* __restrict__ wsw) {
    int t    = blockIdx.x * 256 + threadIdx.x;
    int wid  = t >> 6;                       // 0..1023 == chunk index
    int lane = t & 63;
    int i  = wid >> 7;
    int nt = (wid >> 3) & 15;
    int ks = wid & 7;
    int n = lane & 15, q = lane >> 4;
    const float* src = W + (((size_t)i * 256 + nt * 16 + n) * 256 + ks * 32 + q * 8);
    float4 s0 = *(const float4*)(src);
    float4 s1 = *(const float4*)(src + 4);
    uint4 p;
    p.x = f2bf(s0.x) | (f2bf(s0.y) << 16);
    p.y = f2bf(s0.z) | (f2bf(s0.w) << 16);
    p.z = f2bf(s1.x) | (f2bf(s1.y) << 16);
    p.w = f2bf(s1.z) | (f2bf(s1.w) << 16);
    *(uint4*)(wsw + (size_t)wid * 512 + lane * 8) = p;
}

// ---------------------------------------------------------------------------
// Shared phase A: masked fold-sum (fp32, reference op order) -> ylds in MFMA
// A-fragment order. ushort idx = chunk*544 + q*136 + m*8 + j, chunk=fi*8+ks.
// Write lanes land on 32 distinct banks; frag reads contiguous 16B/lane.
// ---------------------------------------------------------------------------
__device__ __forceinline__ void phase_a(const float* __restrict__ in,
                                        const float* __restrict__ pe,
                                        const float* __restrict__ mn,
                                        const float* __restrict__ mx,
                                        float c, int row0, int tid,
                                        unsigned short* ylds) {
    const int kp = tid & 127;
    const int rh = tid >> 7;
    const int k0 = kp * 2;
    const int jh = kp & 3;
    const int qA = (kp >> 2) & 3;
    const int ksA = kp >> 4;

    float pef[FOLD][2], lo[FOLD][2], hi[FOLD][2];
    #pragma unroll
    for (int f = 0; f < FOLD; ++f) {
        float2 p2 = *(const float2*)(pe + f * ISIZE + k0);
        pef[f][0] = p2.x; pef[f][1] = p2.y;
    }
    #pragma unroll
    for (int i = 0; i < FOLD; ++i) {
        float2 a2 = *(const float2*)(mn + i * ISIZE + k0);
        float2 b2 = *(const float2*)(mx + i * ISIZE + k0);
        lo[i][0] = a2.x * c; lo[i][1] = a2.y * c;
        hi[i][0] = b2.x * c; hi[i][1] = b2.y * c;
    }

    const unsigned wbase = qA * 136 + jh * 2;
    #pragma unroll
    for (int r8 = 0; r8 < 8; ++r8) {
        const int row = rh * 8 + r8;
        float acc[FOLD][2];
        #pragma unroll
        for (int i = 0; i < FOLD; ++i) { acc[i][0] = 0.0f; acc[i][1] = 0.0f; }
        const float* rowp = in + (size_t)(row0 + row) * IN_F + k0;
        #pragma unroll
        for (int f = 0; f < FOLD; ++f) {
            float2 x2 = *(const float2*)(rowp + f * ISIZE);
            float xv0 = fminf(fmaxf(x2.x, -c), c) + pef[f][0];
            float xv1 = fminf(fmaxf(x2.y, -c), c) + pef[f][1];
            #pragma unroll
            for (int i = 0; i < FOLD; ++i) {
                if (xv0 >= lo[i][0] && xv0 <= hi[i][0]) acc[i][0] += xv0;
                if (xv1 >= lo[i][1] && xv1 <= hi[i][1]) acc[i][1] += xv1;
            }
        }
        #pragma unroll
        for (int i = 0; i < FOLD; ++i) {
            unsigned us = f2bf(acc[i][0]) | (f2bf(acc[i][1]) << 16);
            *(unsigned*)&ylds[(i * 8 + ksA) * 544 + wbase + row * 8] = us;
        }
    }
}

// ---------------------------------------------------------------------------
// Kernel 3a (fast path): phase A + MFMA with pre-converted bf16 W fragments.
// ---------------------------------------------------------------------------
__global__ __launch_bounds__(256, 2)
void fold_linear_mfma(const float* __restrict__ in,
                      const unsigned short* __restrict__ wsw,
                      const float* __restrict__ pe,
                      const float* __restrict__ mn,
                      const float* __restrict__ mx,
                      const unsigned int* __restrict__ maxbits,
                      float* __restrict__ out) {
    __shared__ __align__(16) unsigned short ylds[64 * 544];   // 69632 B

    const int tid  = threadIdx.x;
    const int row0 = blockIdx.x * TBM;
    const float mabs = __uint_as_float(*maxbits);
    const float c    = (mabs / 127.0f) * 127.0f;

    phase_a(in, pe, mn, mx, c, row0, tid, ylds);
    __syncthreads();

    const int lane = tid & 63;
    const int wv   = tid >> 6;
    const int mrow = lane & 15;
    const int quad = lane >> 4;

    #pragma unroll
    for (int ff = 0; ff < 2; ++ff) {
        const int fi = wv * 2 + ff;
        f32x4 acc[16];
        #pragma unroll
        for (int nt = 0; nt < 16; ++nt) acc[nt] = (f32x4){0.f, 0.f, 0.f, 0.f};

        #pragma unroll
        for (int kk = 0; kk < 8; ++kk) {
            const short8 a = *(const short8*)&ylds[(fi * 8 + kk) * 544 + quad * 136 + mrow * 8];
            const unsigned short* wb = wsw + ((size_t)(fi * 16) * 8 + kk) * 512 + lane * 8;
            #pragma unroll
            for (int nt = 0; nt < 16; ++nt) {
                const short8 b = *(const short8*)(wb + (size_t)nt * 8 * 512);
                acc[nt] = __builtin_amdgcn_mfma_f32_16x16x32_bf16(a, b, acc[nt], 0, 0, 0);
            }
        }
        const int col0 = fi * 256 + mrow;
        #pragma unroll
        for (int nt = 0; nt < 16; ++nt) {
            #pragma unroll
            for (int rg = 0; rg < 4; ++rg) {
                out[(size_t)(row0 + quad * 4 + rg) * OUT_F + col0 + nt * 16] = acc[nt][rg];
            }
        }
    }
}

// ---------------------------------------------------------------------------
// Kernel 3b (safe path): phase A + MFMA loading W fp32 directly from d_in[1],
// converting to bf16 B-fragments in registers. Uses only 4 B of d_ws total.
// B-frag for lane: B[k=quad*8+j][n=mrow] = W[fi][nt*16+mrow][kk*32+quad*8+j]
// = 8 consecutive fp32 -> two float4 loads (L2-resident, W = 2 MB).
// ---------------------------------------------------------------------------
__global__ __launch_bounds__(256, 2)
void fold_linear_mfma_direct(const float* __restrict__ in,
                             const float* __restrict__ W,
                             const float* __restrict__ pe,
                             const float* __restrict__ mn,
                             const float* __restrict__ mx,
                             const unsigned int* __restrict__ maxbits,
                             float* __restrict__ out) {
    __shared__ __align__(16) unsigned short ylds[64 * 544];   // 69632 B

    const int tid  = threadIdx.x;
    const int row0 = blockIdx.x * TBM;
    const float mabs = __uint_as_float(*maxbits);
    const float c    = (mabs / 127.0f) * 127.0f;

    phase_a(in, pe, mn, mx, c, row0, tid, ylds);
    __syncthreads();

    const int lane = tid & 63;
    const int wv   = tid >> 6;
    const int mrow = lane & 15;
    const int quad = lane >> 4;

    #pragma unroll
    for (int ff = 0; ff < 2; ++ff) {
        const int fi = wv * 2 + ff;
        f32x4 acc[16];
        #pragma unroll
        for (int nt = 0; nt < 16; ++nt) acc[nt] = (f32x4){0.f, 0.f, 0.f, 0.f};

        #pragma unroll
        for (int kk = 0; kk < 8; ++kk) {
            const short8 a = *(const short8*)&ylds[(fi * 8 + kk) * 544 + quad * 136 + mrow * 8];
            const float* wb = W + ((size_t)(fi * 256 + mrow) * 256 + kk * 32 + quad * 8);
            #pragma unroll
            for (int nt = 0; nt < 16; ++nt) {
                const float4 w0 = *(const float4*)(wb + (size_t)nt * 16 * 256);
                const float4 w1 = *(const float4*)(wb + (size_t)nt * 16 * 256 + 4);
                union { uint4 u; short8 s; } cv;
                cv.u.x = f2bf(w0.x) | (f2bf(w0.y) << 16);
                cv.u.y = f2bf(w0.z) | (f2bf(w0.w) << 16);
                cv.u.z = f2bf(w1.x) | (f2bf(w1.y) << 16);
                cv.u.w = f2bf(w1.z) | (f2bf(w1.w) << 16);
                acc[nt] = __builtin_amdgcn_mfma_f32_16x16x32_bf16(a, cv.s, acc[nt], 0, 0, 0);
            }
        }
        const int col0 = fi * 256 + mrow;
        #pragma unroll
        for (int nt = 0; nt < 16; ++nt) {
            #pragma unroll
            for (int rg = 0; rg < 4; ++rg) {
                out[(size_t)(row0 + quad * 4 + rg) * OUT_F + col0 + nt * 16] = acc[nt][rg];
            }
        }
    }
}

extern "C" void kernel_launch(void* const* d_in, const int* in_sizes, int n_in,
                              void* d_out, int out_size, void* d_ws, size_t ws_size,
                              hipStream_t stream) {
    const float* in = (const float*)d_in[0];   // [8192, 2048]
    const float* W  = (const float*)d_in[1];   // [8, 256, 256]
    const float* pe = (const float*)d_in[2];   // [1, 8, 256]
    const float* mn = (const float*)d_in[3];   // [1, 8, 256]
    const float* mx = (const float*)d_in[4];   // [1, 8, 256]
    float* out = (float*)d_out;                // [8192, 2048]

    unsigned int* maxbits = (unsigned int*)d_ws;
    const size_t WSW_NEED = 1024 + (size_t)FOLD * 256 * 256 * 2;   // 1,049,600 B

    // ws is re-poisoned 0xAA before every timed launch — zero the scalar.
    hipMemsetAsync(maxbits, 0, sizeof(unsigned int), stream);

    absmax_kernel<<<4096, 256, 0, stream>>>((const float4*)in, maxbits);

    if (ws_size >= WSW_NEED) {
        // fast path: pre-converted bf16 W table in d_ws (fits)
        unsigned short* wsw = (unsigned short*)((char*)d_ws + 1024);
        convert_w_kernel<<<256, 256, 0, stream>>>(W, wsw);
        fold_linear_mfma<<<NBLK, 256, 0, stream>>>(in, wsw, pe, mn, mx, maxbits, out);
    } else {
        // safe path: W read as fp32 directly, converted in registers
        fold_linear_mfma_direct<<<NBLK, 256, 0, stream>>>(in, W, pe, mn, mx, maxbits, out);
    }
}

// Round 4
// 153.602 us; speedup vs baseline: 2.7179x; 1.5965x over previous
//
#include <hip/hip_runtime.h>

#define FOLD  8
#define ISIZE 256
#define IN_F  2048
#define OUT_F 2048
#define TBM   32                  // batch rows per block
#define NBLK  (8192 / TBM)        // 256 blocks = 1 per CU
#define CHW   1104                // ushorts per (fold,ks) chunk (2x544 + 16 pad)

typedef __attribute__((ext_vector_type(8))) short short8;   // 8 bf16 (4 VGPRs)
typedef __attribute__((ext_vector_type(4))) float f32x4;    // MFMA C/D frag

// round-to-nearest-even fp32 -> bf16
__device__ __forceinline__ unsigned f2bf(float f) {
    unsigned u = __float_as_uint(f);
    u += 0x7FFFu + ((u >> 16) & 1u);
    return (u >> 16);
}

// ---------------------------------------------------------------------------
// Kernel 1: abs-max. 256 blocks x 256 threads, 64 float4 each (exact cover).
// mode=1: write per-block partial (no atomics). mode=0: atomicMax fallback.
// ---------------------------------------------------------------------------
__global__ __launch_bounds__(256)
void absmax_kernel(const float4* __restrict__ in,
                   float* __restrict__ partials,
                   unsigned int* __restrict__ scal, int mode) {
    const int idx = blockIdx.x * 256 + threadIdx.x;   // 65536 threads
    float m0 = 0.f, m1 = 0.f, m2 = 0.f, m3 = 0.f;
    #pragma unroll
    for (int k = 0; k < 64; k += 4) {
        float4 a = in[idx + (k    ) * 65536];
        float4 b = in[idx + (k + 1) * 65536];
        float4 c = in[idx + (k + 2) * 65536];
        float4 d = in[idx + (k + 3) * 65536];
        m0 = fmaxf(m0, fmaxf(fmaxf(fabsf(a.x), fabsf(a.y)), fmaxf(fabsf(a.z), fabsf(a.w))));
        m1 = fmaxf(m1, fmaxf(fmaxf(fabsf(b.x), fabsf(b.y)), fmaxf(fabsf(b.z), fabsf(b.w))));
        m2 = fmaxf(m2, fmaxf(fmaxf(fabsf(c.x), fabsf(c.y)), fmaxf(fabsf(c.z), fabsf(c.w))));
        m3 = fmaxf(m3, fmaxf(fmaxf(fabsf(d.x), fabsf(d.y)), fmaxf(fabsf(d.z), fabsf(d.w))));
    }
    float m = fmaxf(fmaxf(m0, m1), fmaxf(m2, m3));
    #pragma unroll
    for (int off = 32; off > 0; off >>= 1)
        m = fmaxf(m, __shfl_down(m, off, 64));
    __shared__ float sm[4];
    int lane = threadIdx.x & 63, wv = threadIdx.x >> 6;
    if (lane == 0) sm[wv] = m;
    __syncthreads();
    if (threadIdx.x == 0) {
        float r = fmaxf(fmaxf(sm[0], sm[1]), fmaxf(sm[2], sm[3]));
        if (mode) partials[blockIdx.x] = r;
        else      atomicMax(scal, __float_as_uint(r));
    }
}

// ---------------------------------------------------------------------------
// Kernel 2 (only if ws fits): W fp32 -> bf16 in MFMA B-fragment order.
// chunk wid=(i*16+nt)*8+ks: B[k=q*8+j][n=lane&15]=W[i][nt*16+n][ks*32+q*8+j]
// ---------------------------------------------------------------------------
__global__ void convert_w_kernel(const float* __restrict__ W,
                                 unsigned short* __restrict__ wsw) {
    int t    = blockIdx.x * 256 + threadIdx.x;
    int wid  = t >> 6;
    int lane = t & 63;
    int i  = wid >> 7;
    int nt = (wid >> 3) & 15;
    int ks = wid & 7;
    int n = lane & 15, q = lane >> 4;
    const float* src = W + (((size_t)i * 256 + nt * 16 + n) * 256 + ks * 32 + q * 8);
    float4 s0 = *(const float4*)(src);
    float4 s1 = *(const float4*)(src + 4);
    uint4 p;
    p.x = f2bf(s0.x) | (f2bf(s0.y) << 16);
    p.y = f2bf(s0.z) | (f2bf(s0.w) << 16);
    p.z = f2bf(s1.x) | (f2bf(s1.y) << 16);
    p.w = f2bf(s1.z) | (f2bf(s1.w) << 16);
    *(uint4*)(wsw + (size_t)wid * 512 + lane * 8) = p;
}

// ---------------------------------------------------------------------------
// Main kernel: 256 blocks x 512 threads, 32 batch rows per block.
//   prologue: reduce 256 abs-max partials (or read atomic scalar)
//   Phase A : masked fold-sum (fp32, reference op order) -> ylds (A-frag order)
//   Phase B : bf16 MFMA, W either pre-converted (PRECONV) or fp32->bf16 in regs
// ylds ushort idx = (fi*8+ks)*CHW + (row>>4)*544 + q*136 + (row&15)*8 + j
// ---------------------------------------------------------------------------
template<int PRECONV>
__global__ __launch_bounds__(512, 2)
void fold_main(const float* __restrict__ in,
               const float* __restrict__ W,
               const unsigned short* __restrict__ wsw,
               const float* __restrict__ pe,
               const float* __restrict__ mn,
               const float* __restrict__ mx,
               const float* __restrict__ partials,
               const unsigned int* __restrict__ scal,
               int npart,
               float* __restrict__ out) {
    __shared__ __align__(16) unsigned short ylds[64 * CHW];   // 141,312 B
    __shared__ float sred[8];

    const int tid  = threadIdx.x;
    const int lane = tid & 63;
    const int wv   = tid >> 6;
    const int row0 = blockIdx.x * TBM;

    // ---- global abs-max ----
    float mabs;
    if (npart > 0) {
        float v = (tid < npart) ? partials[tid] : 0.0f;
        #pragma unroll
        for (int off = 32; off > 0; off >>= 1)
            v = fmaxf(v, __shfl_down(v, off, 64));
        if (lane == 0) sred[wv] = v;
        __syncthreads();
        float r = sred[0];
        #pragma unroll
        for (int i = 1; i < 8; ++i) r = fmaxf(r, sred[i]);
        mabs = r;
    } else {
        mabs = __uint_as_float(*scal);
    }
    const float c = (mabs / 127.0f) * 127.0f;   // reference fp32 op order

    // ---- Phase A ----
    {
        const int kp  = tid & 127;      // column pair: k0 = 2*kp
        const int rq  = tid >> 7;       // row quarter: rows rq*8 .. rq*8+7
        const int k0  = kp * 2;
        const int jh  = kp & 3;
        const int qA  = (kp >> 2) & 3;
        const int ksA = kp >> 4;

        float pef[FOLD][2], lo[FOLD][2], hi[FOLD][2];
        #pragma unroll
        for (int f = 0; f < FOLD; ++f) {
            float2 p2 = *(const float2*)(pe + f * ISIZE + k0);
            pef[f][0] = p2.x; pef[f][1] = p2.y;
        }
        #pragma unroll
        for (int i = 0; i < FOLD; ++i) {
            float2 a2 = *(const float2*)(mn + i * ISIZE + k0);
            float2 b2 = *(const float2*)(mx + i * ISIZE + k0);
            lo[i][0] = a2.x * c; lo[i][1] = a2.y * c;
            hi[i][0] = b2.x * c; hi[i][1] = b2.y * c;
        }

        #pragma unroll
        for (int r8 = 0; r8 < 8; ++r8) {
            const int row = rq * 8 + r8;
            const float* rowp = in + (size_t)(row0 + row) * IN_F + k0;
            // batch the 8 input loads for this row before computing
            float2 xr[FOLD];
            #pragma unroll
            for (int f = 0; f < FOLD; ++f) xr[f] = *(const float2*)(rowp + f * ISIZE);

            float acc[FOLD][2];
            #pragma unroll
            for (int i = 0; i < FOLD; ++i) { acc[i][0] = 0.0f; acc[i][1] = 0.0f; }
            #pragma unroll
            for (int f = 0; f < FOLD; ++f) {
                float xv0 = fminf(fmaxf(xr[f].x, -c), c) + pef[f][0];
                float xv1 = fminf(fmaxf(xr[f].y, -c), c) + pef[f][1];
                #pragma unroll
                for (int i = 0; i < FOLD; ++i) {
                    if (xv0 >= lo[i][0] && xv0 <= hi[i][0]) acc[i][0] += xv0;
                    if (xv1 >= lo[i][1] && xv1 <= hi[i][1]) acc[i][1] += xv1;
                }
            }
            const unsigned base = (unsigned)((row >> 4) * 544 + qA * 136 + (row & 15) * 8 + jh * 2);
            #pragma unroll
            for (int i = 0; i < FOLD; ++i) {
                unsigned us = f2bf(acc[i][0]) | (f2bf(acc[i][1]) << 16);
                *(unsigned*)&ylds[(i * 8 + ksA) * CHW + base] = us;
            }
        }
    }
    __syncthreads();

    // ---- Phase B ---- wave = fold
    {
        const int fi   = wv;
        const int mrow = lane & 15;
        const int quad = lane >> 4;

        // cache all 16 A-fragments (8 k-steps x 2 m-tiles) in registers
        short8 afr[8][2];
        #pragma unroll
        for (int kk = 0; kk < 8; ++kk) {
            #pragma unroll
            for (int mt = 0; mt < 2; ++mt)
                afr[kk][mt] = *(const short8*)&ylds[(fi * 8 + kk) * CHW + mt * 544 + quad * 136 + mrow * 8];
        }

        const int col0 = fi * 256 + mrow;
        #pragma unroll 2
        for (int nt = 0; nt < 16; ++nt) {
            f32x4 a0 = (f32x4){0.f, 0.f, 0.f, 0.f};
            f32x4 a1 = (f32x4){0.f, 0.f, 0.f, 0.f};
            if (PRECONV) {
                const unsigned short* wb = wsw + ((size_t)(fi * 16 + nt) * 8) * 512 + lane * 8;
                uint4 wq[8];
                #pragma unroll
                for (int kk = 0; kk < 8; ++kk) wq[kk] = *(const uint4*)(wb + kk * 512);
                #pragma unroll
                for (int kk = 0; kk < 8; ++kk) {
                    union { uint4 u; short8 s; } cv; cv.u = wq[kk];
                    a0 = __builtin_amdgcn_mfma_f32_16x16x32_bf16(afr[kk][0], cv.s, a0, 0, 0, 0);
                    a1 = __builtin_amdgcn_mfma_f32_16x16x32_bf16(afr[kk][1], cv.s, a1, 0, 0, 0);
                }
            } else {
                const float* wb = W + ((size_t)(fi * 256 + nt * 16 + mrow) * 256 + quad * 8);
                float4 w[16];
                #pragma unroll
                for (int kk = 0; kk < 8; ++kk) {
                    w[2 * kk]     = *(const float4*)(wb + kk * 32);
                    w[2 * kk + 1] = *(const float4*)(wb + kk * 32 + 4);
                }
                #pragma unroll
                for (int kk = 0; kk < 8; ++kk) {
                    union { uint4 u; short8 s; } cv;
                    cv.u.x = f2bf(w[2*kk].x)   | (f2bf(w[2*kk].y)   << 16);
                    cv.u.y = f2bf(w[2*kk].z)   | (f2bf(w[2*kk].w)   << 16);
                    cv.u.z = f2bf(w[2*kk+1].x) | (f2bf(w[2*kk+1].y) << 16);
                    cv.u.w = f2bf(w[2*kk+1].z) | (f2bf(w[2*kk+1].w) << 16);
                    a0 = __builtin_amdgcn_mfma_f32_16x16x32_bf16(afr[kk][0], cv.s, a0, 0, 0, 0);
                    a1 = __builtin_amdgcn_mfma_f32_16x16x32_bf16(afr[kk][1], cv.s, a1, 0, 0, 0);
                }
            }
            // C/D layout: col=lane&15, row=quad*4+reg; m-tile 1 is rows +16
            #pragma unroll
            for (int rg = 0; rg < 4; ++rg) {
                out[(size_t)(row0 +      quad * 4 + rg) * OUT_F + col0 + nt * 16] = a0[rg];
                out[(size_t)(row0 + 16 + quad * 4 + rg) * OUT_F + col0 + nt * 16] = a1[rg];
            }
        }
    }
}

extern "C" void kernel_launch(void* const* d_in, const int* in_sizes, int n_in,
                              void* d_out, int out_size, void* d_ws, size_t ws_size,
                              hipStream_t stream) {
    const float* in = (const float*)d_in[0];   // [8192, 2048]
    const float* W  = (const float*)d_in[1];   // [8, 256, 256]
    const float* pe = (const float*)d_in[2];   // [1, 8, 256]
    const float* mn = (const float*)d_in[3];   // [1, 8, 256]
    const float* mx = (const float*)d_in[4];   // [1, 8, 256]
    float* out = (float*)d_out;                // [8192, 2048]

    const size_t PART_OFF  = 16;
    const size_t WSW_OFF   = 4096;
    const size_t WSW_BYTES = (size_t)FOLD * 256 * 256 * 2;   // 1 MB

    unsigned int*   scal     = (unsigned int*)d_ws;
    float*          partials = (float*)((char*)d_ws + PART_OFF);
    unsigned short* wsw      = (unsigned short*)((char*)d_ws + WSW_OFF);

    const bool twostage = ws_size >= PART_OFF + 256 * sizeof(float);   // 1040 B
    const bool preconv  = ws_size >= WSW_OFF + WSW_BYTES;              // ~1.05 MB

    if (!twostage) hipMemsetAsync(d_ws, 0, sizeof(unsigned int), stream);

    absmax_kernel<<<256, 256, 0, stream>>>((const float4*)in, partials, scal,
                                           twostage ? 1 : 0);
    const int npart = twostage ? 256 : 0;
    if (preconv) {
        convert_w_kernel<<<256, 256, 0, stream>>>(W, wsw);
        fold_main<1><<<NBLK, 512, 0, stream>>>(in, W, wsw, pe, mn, mx,
                                               partials, scal, npart, out);
    } else {
        fold_main<0><<<NBLK, 512, 0, stream>>>(in, W, wsw, pe, mn, mx,
                                               partials, scal, npart, out);
    }
}

// Round 5
// 152.759 us; speedup vs baseline: 2.7329x; 1.0055x over previous
//
#include <hip/hip_runtime.h>

#define FOLD  8
#define ISIZE 256
#define IN_F  2048
#define OUT_F 2048
#define TBM   32                  // batch rows per block
#define NBLK  (8192 / TBM)        // 256 blocks, 1 per CU
#define CHW   1104                // ushorts per (fold,ks) chunk (2x544 + 16 pad)

typedef __attribute__((ext_vector_type(8))) short short8;   // 8 bf16 (4 VGPRs)
typedef __attribute__((ext_vector_type(4))) float f32x4;    // MFMA C/D frag

// round-to-nearest-even fp32 -> bf16
__device__ __forceinline__ unsigned f2bf(float f) {
    unsigned u = __float_as_uint(f);
    u += 0x7FFFu + ((u >> 16) & 1u);
    return (u >> 16);
}

// ---------------------------------------------------------------------------
// Kernel 1: abs-max. grid*256 threads, `quota` float4 each (exact cover).
// mode=1: per-block partial (no atomics). mode=0: atomicMax fallback.
// quota kept small-unrolled (x4) so loads pipeline without VGPR spill.
// ---------------------------------------------------------------------------
__global__ __launch_bounds__(256)
void absmax_kernel(const float4* __restrict__ in,
                   float* __restrict__ partials,
                   unsigned int* __restrict__ scal,
                   int quota, int mode) {
    const int nthreads = gridDim.x * 256;
    const int idx = blockIdx.x * 256 + threadIdx.x;
    float m = 0.f;
    #pragma unroll 4
    for (int q = 0; q < quota; ++q) {
        float4 a = in[idx + q * nthreads];
        m = fmaxf(m, fmaxf(fmaxf(fabsf(a.x), fabsf(a.y)),
                           fmaxf(fabsf(a.z), fabsf(a.w))));
    }
    #pragma unroll
    for (int off = 32; off > 0; off >>= 1)
        m = fmaxf(m, __shfl_down(m, off, 64));
    __shared__ float sm[4];
    int lane = threadIdx.x & 63, wv = threadIdx.x >> 6;
    if (lane == 0) sm[wv] = m;
    __syncthreads();
    if (threadIdx.x == 0) {
        float r = fmaxf(fmaxf(sm[0], sm[1]), fmaxf(sm[2], sm[3]));
        if (mode) partials[blockIdx.x] = r;
        else      atomicMax(scal, __float_as_uint(r));
    }
}

// ---------------------------------------------------------------------------
// Kernel 2 (only if ws fits): W fp32 -> bf16 in MFMA B-fragment order.
// chunk wid=(i*16+nt)*8+ks: B[k=q*8+j][n=lane&15]=W[i][nt*16+n][ks*32+q*8+j]
// ---------------------------------------------------------------------------
__global__ void convert_w_kernel(const float* __restrict__ W,
                                 unsigned short* __restrict__ wsw) {
    int t    = blockIdx.x * 256 + threadIdx.x;
    int wid  = t >> 6;
    int lane = t & 63;
    int i  = wid >> 7;
    int nt = (wid >> 3) & 15;
    int ks = wid & 7;
    int n = lane & 15, q = lane >> 4;
    const float* src = W + (((size_t)i * 256 + nt * 16 + n) * 256 + ks * 32 + q * 8);
    float4 s0 = *(const float4*)(src);
    float4 s1 = *(const float4*)(src + 4);
    uint4 p;
    p.x = f2bf(s0.x) | (f2bf(s0.y) << 16);
    p.y = f2bf(s0.z) | (f2bf(s0.w) << 16);
    p.z = f2bf(s1.x) | (f2bf(s1.y) << 16);
    p.w = f2bf(s1.z) | (f2bf(s1.w) << 16);
    *(uint4*)(wsw + (size_t)wid * 512 + lane * 8) = p;
}

// ---------------------------------------------------------------------------
// Main kernel: 256 blocks x 1024 threads (16 waves/CU), 32 rows per block.
//   prologue: reduce npart abs-max partials (or read atomic scalar)
//   Phase A : masked fold-sum (fp32, reference op order) -> ylds (A-frag order)
//             thread owns k-pair (tid&127) and 4 rows ((tid>>7)*4 ..+3)
//   Phase B : wave = (fold, nt-half): 8 nt-tiles x 8 kk x 2 m-tiles MFMA
// ylds ushort idx = (fi*8+ks)*CHW + (row>>4)*544 + q*136 + (row&15)*8 + j
// ---------------------------------------------------------------------------
template<int PRECONV>
__global__ __launch_bounds__(1024, 1)
void fold_main(const float* __restrict__ in,
               const float* __restrict__ W,
               const unsigned short* __restrict__ wsw,
               const float* __restrict__ pe,
               const float* __restrict__ mn,
               const float* __restrict__ mx,
               const float* __restrict__ partials,
               const unsigned int* __restrict__ scal,
               int npart,
               float* __restrict__ out) {
    __shared__ __align__(16) unsigned short ylds[64 * CHW];   // 141,312 B
    __shared__ float sred[16];

    const int tid  = threadIdx.x;
    const int lane = tid & 63;
    const int wv   = tid >> 6;          // 0..15
    const int row0 = blockIdx.x * TBM;

    // ---- global abs-max ----
    float mabs;
    if (npart > 0) {
        float v = (tid < npart) ? partials[tid] : 0.0f;
        #pragma unroll
        for (int off = 32; off > 0; off >>= 1)
            v = fmaxf(v, __shfl_down(v, off, 64));
        if (lane == 0) sred[wv] = v;
        __syncthreads();
        float r = sred[0];
        #pragma unroll
        for (int i = 1; i < 16; ++i) r = fmaxf(r, sred[i]);
        mabs = r;
    } else {
        mabs = __uint_as_float(*scal);
    }
    const float c = (mabs / 127.0f) * 127.0f;   // reference fp32 op order

    // ---- Phase A ----
    {
        const int kp  = tid & 127;      // k-pair: k0 = 2*kp
        const int rq  = tid >> 7;       // row quarter-of-8: rows rq*4..rq*4+3
        const int k0  = kp * 2;
        const int jh  = kp & 3;
        const int qA  = (kp >> 2) & 3;
        const int ksA = kp >> 4;

        float pef[FOLD][2], lo[FOLD][2], hi[FOLD][2];
        #pragma unroll
        for (int f = 0; f < FOLD; ++f) {
            float2 p2 = *(const float2*)(pe + f * ISIZE + k0);
            pef[f][0] = p2.x; pef[f][1] = p2.y;
        }
        #pragma unroll
        for (int i = 0; i < FOLD; ++i) {
            float2 a2 = *(const float2*)(mn + i * ISIZE + k0);
            float2 b2 = *(const float2*)(mx + i * ISIZE + k0);
            lo[i][0] = a2.x * c; lo[i][1] = a2.y * c;
            hi[i][0] = b2.x * c; hi[i][1] = b2.y * c;
        }

        #pragma unroll
        for (int r4 = 0; r4 < 4; ++r4) {
            const int row = rq * 4 + r4;
            const float* rowp = in + (size_t)(row0 + row) * IN_F + k0;
            float2 xr[FOLD];
            #pragma unroll
            for (int f = 0; f < FOLD; ++f) xr[f] = *(const float2*)(rowp + f * ISIZE);

            float acc[FOLD][2];
            #pragma unroll
            for (int i = 0; i < FOLD; ++i) { acc[i][0] = 0.0f; acc[i][1] = 0.0f; }
            #pragma unroll
            for (int f = 0; f < FOLD; ++f) {
                float xv0 = fminf(fmaxf(xr[f].x, -c), c) + pef[f][0];
                float xv1 = fminf(fmaxf(xr[f].y, -c), c) + pef[f][1];
                #pragma unroll
                for (int i = 0; i < FOLD; ++i) {
                    if (xv0 >= lo[i][0] && xv0 <= hi[i][0]) acc[i][0] += xv0;
                    if (xv1 >= lo[i][1] && xv1 <= hi[i][1]) acc[i][1] += xv1;
                }
            }
            const unsigned base = (unsigned)((row >> 4) * 544 + qA * 136 + (row & 15) * 8 + jh * 2);
            #pragma unroll
            for (int i = 0; i < FOLD; ++i) {
                unsigned us = f2bf(acc[i][0]) | (f2bf(acc[i][1]) << 16);
                *(unsigned*)&ylds[(i * 8 + ksA) * CHW + base] = us;
            }
        }
    }
    __syncthreads();

    // ---- Phase B ---- wave = (fold, nt-half)
    {
        const int fi   = wv >> 1;
        const int nh   = wv & 1;
        const int mrow = lane & 15;
        const int quad = lane >> 4;

        // cache this fold's 16 A-fragments (8 k-steps x 2 m-tiles): 64 VGPRs
        short8 afr[8][2];
        #pragma unroll
        for (int kk = 0; kk < 8; ++kk) {
            #pragma unroll
            for (int mt = 0; mt < 2; ++mt)
                afr[kk][mt] = *(const short8*)&ylds[(fi * 8 + kk) * CHW + mt * 544 + quad * 136 + mrow * 8];
        }

        const int col0 = fi * 256 + mrow;
        #pragma unroll 2
        for (int nt8 = 0; nt8 < 8; ++nt8) {
            const int ntg = nh * 8 + nt8;
            f32x4 a0 = (f32x4){0.f, 0.f, 0.f, 0.f};
            f32x4 a1 = (f32x4){0.f, 0.f, 0.f, 0.f};
            if (PRECONV) {
                const unsigned short* wb = wsw + ((size_t)(fi * 16 + ntg) * 8) * 512 + lane * 8;
                uint4 wq[8];
                #pragma unroll
                for (int kk = 0; kk < 8; ++kk) wq[kk] = *(const uint4*)(wb + kk * 512);
                #pragma unroll
                for (int kk = 0; kk < 8; ++kk) {
                    union { uint4 u; short8 s; } cv; cv.u = wq[kk];
                    a0 = __builtin_amdgcn_mfma_f32_16x16x32_bf16(afr[kk][0], cv.s, a0, 0, 0, 0);
                    a1 = __builtin_amdgcn_mfma_f32_16x16x32_bf16(afr[kk][1], cv.s, a1, 0, 0, 0);
                }
            } else {
                const float* wb = W + ((size_t)(fi * 256 + ntg * 16 + mrow) * 256 + quad * 8);
                float4 w[16];
                #pragma unroll
                for (int kk = 0; kk < 8; ++kk) {
                    w[2 * kk]     = *(const float4*)(wb + kk * 32);
                    w[2 * kk + 1] = *(const float4*)(wb + kk * 32 + 4);
                }
                #pragma unroll
                for (int kk = 0; kk < 8; ++kk) {
                    union { uint4 u; short8 s; } cv;
                    cv.u.x = f2bf(w[2*kk].x)   | (f2bf(w[2*kk].y)   << 16);
                    cv.u.y = f2bf(w[2*kk].z)   | (f2bf(w[2*kk].w)   << 16);
                    cv.u.z = f2bf(w[2*kk+1].x) | (f2bf(w[2*kk+1].y) << 16);
                    cv.u.w = f2bf(w[2*kk+1].z) | (f2bf(w[2*kk+1].w) << 16);
                    a0 = __builtin_amdgcn_mfma_f32_16x16x32_bf16(afr[kk][0], cv.s, a0, 0, 0, 0);
                    a1 = __builtin_amdgcn_mfma_f32_16x16x32_bf16(afr[kk][1], cv.s, a1, 0, 0, 0);
                }
            }
            // C/D layout: col=lane&15, row=quad*4+reg; m-tile 1 is rows +16
            #pragma unroll
            for (int rg = 0; rg < 4; ++rg) {
                out[(size_t)(row0 +      quad * 4 + rg) * OUT_F + col0 + ntg * 16] = a0[rg];
                out[(size_t)(row0 + 16 + quad * 4 + rg) * OUT_F + col0 + ntg * 16] = a1[rg];
            }
        }
    }
}

extern "C" void kernel_launch(void* const* d_in, const int* in_sizes, int n_in,
                              void* d_out, int out_size, void* d_ws, size_t ws_size,
                              hipStream_t stream) {
    const float* in = (const float*)d_in[0];   // [8192, 2048]
    const float* W  = (const float*)d_in[1];   // [8, 256, 256]
    const float* pe = (const float*)d_in[2];   // [1, 8, 256]
    const float* mn = (const float*)d_in[3];   // [1, 8, 256]
    const float* mx = (const float*)d_in[4];   // [1, 8, 256]
    float* out = (float*)d_out;                // [8192, 2048]

    const size_t PART_OFF  = 16;
    const size_t WSW_OFF   = 8192;
    const size_t WSW_BYTES = (size_t)FOLD * 256 * 256 * 2;   // 1 MB

    unsigned int*   scal     = (unsigned int*)d_ws;
    float*          partials = (float*)((char*)d_ws + PART_OFF);
    unsigned short* wsw      = (unsigned short*)((char*)d_ws + WSW_OFF);

    const bool preconv = ws_size >= WSW_OFF + WSW_BYTES;

    int npart;
    if (ws_size >= PART_OFF + 1024 * sizeof(float)) {          // 4112 B
        absmax_kernel<<<1024, 256, 0, stream>>>((const float4*)in, partials, scal, 16, 1);
        npart = 1024;
    } else if (ws_size >= PART_OFF + 256 * sizeof(float)) {    // 1040 B
        absmax_kernel<<<256, 256, 0, stream>>>((const float4*)in, partials, scal, 64, 1);
        npart = 256;
    } else {
        hipMemsetAsync(d_ws, 0, sizeof(unsigned int), stream);
        absmax_kernel<<<256, 256, 0, stream>>>((const float4*)in, partials, scal, 64, 0);
        npart = 0;
    }

    if (preconv) {
        convert_w_kernel<<<256, 256, 0, stream>>>(W, wsw);
        fold_main<1><<<NBLK, 1024, 0, stream>>>(in, W, wsw, pe, mn, mx,
                                                partials, scal, npart, out);
    } else {
        fold_main<0><<<NBLK, 1024, 0, stream>>>(in, W, wsw, pe, mn, mx,
                                                partials, scal, npart, out);
    }
}